// Round 1
// baseline (504.535 us; speedup 1.0000x reference)
//
#include <hip/hip_runtime.h>

typedef unsigned short u16;
typedef __attribute__((ext_vector_type(8))) short bf16x8;
typedef __attribute__((ext_vector_type(4))) float f32x4;

#define BB 64
#define NN 5000
#define DD 128
#define EROW 640128   // (NN+1)*DD
#define CROW 640000   // NN*DD

__device__ __forceinline__ u16 f2bf(float f){
  unsigned u = __builtin_bit_cast(unsigned, f);
  u += 0x7fffu + ((u >> 16) & 1u);   // round-to-nearest-even
  return (u16)(u >> 16);
}
__device__ __forceinline__ float bf2f(u16 h){
  unsigned u = ((unsigned)h) << 16;
  return __builtin_bit_cast(float, u);
}

// ---------------- k0: weight bf16 conversion, accumulator zeroing, depot copy ----------------
__global__ __launch_bounds__(256) void k0_prep(
    const float* __restrict__ wl, const float* __restrict__ wr,
    const float* __restrict__ wcmb, const float* __restrict__ wff,
    const float* __restrict__ emb, float* __restrict__ out,
    u16* __restrict__ wbf, float* __restrict__ sums, float* __restrict__ sumsq)
{
  int t = blockIdx.x * 256 + threadIdx.x;   // grid covers exactly 81920
  if      (t < 16384) wbf[t] = f2bf(wl[t]);
  else if (t < 32768) wbf[t] = f2bf(wr[t - 16384]);
  else if (t < 65536) wbf[t] = f2bf(wcmb[t - 32768]);
  else                wbf[t] = f2bf(wff[t - 65536]);
  if (t < 8192){
    sums[t] = 0.f; sumsq[t] = 0.f;
    int b = t >> 7, d = t & 127;
    out[(size_t)b * EROW + d] = emb[(size_t)b * EROW + d];   // depot row passthrough
  }
}

// ---------------- k1: fused gather + 3 GEMMs + residual, writes 'added' to out, stats atomics ----------------
__global__ __launch_bounds__(256, 2)
void k1_main(const int2* __restrict__ sol, const float* __restrict__ emb,
             const u16* __restrict__ wbf, const float* __restrict__ b_comb,
             const float* __restrict__ b_ff, float* __restrict__ out,
             float* __restrict__ sums, float* __restrict__ sumsq)
{
  const int tid  = threadIdx.x;
  const int lane = tid & 63;
  const int wave = tid >> 6;
  const int q    = lane >> 4;
  const int c    = lane & 15;
  const int tile = blockIdx.x;
  const int b    = blockIdx.y;
  const int rbase = tile * 64;
  const int RC = min(64, NN - rbase);

  // pad 136 (=128+8): rows stay 16B-aligned (272B stride), bank offset 4/row -> 2-way (free)
  __shared__ u16 P0[64][136];   // left  -> info -> (dead)
  __shared__ u16 P1[64][136];   // right -> h
  __shared__ u16 P2[64][136];   // cust (live to end)
  __shared__ int sIL[64], sIR[64];

  if (tid < 64){
    int r = rbase + tid; r = min(r, NN - 1);
    int2 p = sol[(size_t)b * NN + r];
    sIL[tid] = p.x; sIR[tid] = p.y;
  }
  __syncthreads();

  { // gather + fp32->bf16 into LDS
    const int i = tid >> 2, sub = tid & 3;
    const float* embB = emb + (size_t)b * EROW;
    if (i < RC){
      const float4* vC = (const float4*)(embB + (size_t)(rbase + i + 1) * DD) + sub * 8;
      const float4* vL = (const float4*)(embB + (size_t)sIL[i] * DD) + sub * 8;
      const float4* vR = (const float4*)(embB + (size_t)sIR[i] * DD) + sub * 8;
      #pragma unroll
      for (int j = 0; j < 8; ++j){
        float4 a = vL[j], bb = vR[j], cc = vC[j];
        int col = sub * 32 + j * 4;
        ushort4 ua = {f2bf(a.x),  f2bf(a.y),  f2bf(a.z),  f2bf(a.w)};
        ushort4 ub = {f2bf(bb.x), f2bf(bb.y), f2bf(bb.z), f2bf(bb.w)};
        ushort4 uc = {f2bf(cc.x), f2bf(cc.y), f2bf(cc.z), f2bf(cc.w)};
        *(ushort4*)&P0[i][col] = ua;
        *(ushort4*)&P1[i][col] = ub;
        *(ushort4*)&P2[i][col] = uc;
      }
    } else {
      ushort4 z = {0,0,0,0};
      #pragma unroll
      for (int j = 0; j < 8; ++j){
        int col = sub * 32 + j * 4;
        *(ushort4*)&P0[i][col] = z;
        *(ushort4*)&P1[i][col] = z;
        *(ushort4*)&P2[i][col] = z;
      }
    }
  }
  __syncthreads();

  const int n0 = wave * 32 + c;   // this wave owns output cols [wave*32, wave*32+32)
  const int n1 = n0 + 16;

  const u16* wl = wbf;            // [128][128] bf16
  const u16* wr = wbf + 16384;    // [128][128]
  const u16* wc = wbf + 32768;    // [128][256]
  const u16* wf = wbf + 65536;    // [128][128]

  const f32x4 fz = {0.f, 0.f, 0.f, 0.f};
  f32x4 acc[4][2];

  // ---- GEMM1: info = left @ Wl^T + right @ Wr^T (K = 128+128) ----
  #pragma unroll
  for (int mt = 0; mt < 4; ++mt){ acc[mt][0] = fz; acc[mt][1] = fz; }
  #pragma unroll
  for (int ks = 0; ks < 8; ++ks){
    const u16* W = (ks < 4) ? wl : wr;
    const int kk = (ks & 3) * 32 + q * 8;
    bf16x8 b0 = *(const bf16x8*)(W + n0 * 128 + kk);
    bf16x8 b1 = *(const bf16x8*)(W + n1 * 128 + kk);
    #pragma unroll
    for (int mt = 0; mt < 4; ++mt){
      bf16x8 a = *(const bf16x8*)&((ks < 4) ? P0 : P1)[mt * 16 + c][kk];
      acc[mt][0] = __builtin_amdgcn_mfma_f32_16x16x32_bf16(a, b0, acc[mt][0], 0, 0, 0);
      acc[mt][1] = __builtin_amdgcn_mfma_f32_16x16x32_bf16(a, b1, acc[mt][1], 0, 0, 0);
    }
  }
  __syncthreads();   // all reads of P0/P1 done
  #pragma unroll
  for (int mt = 0; mt < 4; ++mt){
    #pragma unroll
    for (int r = 0; r < 4; ++r){
      int m = mt * 16 + q * 4 + r;   // C/D layout: row=(lane>>4)*4+reg, col=lane&15
      P0[m][n0] = f2bf(acc[mt][0][r]);
      P0[m][n1] = f2bf(acc[mt][1][r]);
    }
  }
  __syncthreads();

  // ---- GEMM2: h = relu([cust | info] @ Wcomb^T + b_comb) (K = 256) ----
  #pragma unroll
  for (int mt = 0; mt < 4; ++mt){ acc[mt][0] = fz; acc[mt][1] = fz; }
  #pragma unroll
  for (int ks = 0; ks < 8; ++ks){
    const int kk = (ks & 3) * 32 + q * 8;
    const int kg = ks * 32 + q * 8;
    bf16x8 b0 = *(const bf16x8*)(wc + n0 * 256 + kg);
    bf16x8 b1 = *(const bf16x8*)(wc + n1 * 256 + kg);
    #pragma unroll
    for (int mt = 0; mt < 4; ++mt){
      bf16x8 a = *(const bf16x8*)&((ks < 4) ? P2 : P0)[mt * 16 + c][kk];
      acc[mt][0] = __builtin_amdgcn_mfma_f32_16x16x32_bf16(a, b0, acc[mt][0], 0, 0, 0);
      acc[mt][1] = __builtin_amdgcn_mfma_f32_16x16x32_bf16(a, b1, acc[mt][1], 0, 0, 0);
    }
  }
  __syncthreads();   // all reads of P0 (info) done before P1 overwrite below? (P1 dead since GEMM1)
  {
    float bc0 = b_comb[n0], bc1 = b_comb[n1];
    #pragma unroll
    for (int mt = 0; mt < 4; ++mt){
      #pragma unroll
      for (int r = 0; r < 4; ++r){
        int m = mt * 16 + q * 4 + r;
        P1[m][n0] = f2bf(fmaxf(acc[mt][0][r] + bc0, 0.f));
        P1[m][n1] = f2bf(fmaxf(acc[mt][1][r] + bc1, 0.f));
      }
    }
  }
  __syncthreads();

  // ---- GEMM3: h2 = h @ Wff^T + b_ff;  added = cust + h2 ----
  #pragma unroll
  for (int mt = 0; mt < 4; ++mt){ acc[mt][0] = fz; acc[mt][1] = fz; }
  #pragma unroll
  for (int ks = 0; ks < 4; ++ks){
    const int kk = ks * 32 + q * 8;
    bf16x8 b0 = *(const bf16x8*)(wf + n0 * 128 + kk);
    bf16x8 b1 = *(const bf16x8*)(wf + n1 * 128 + kk);
    #pragma unroll
    for (int mt = 0; mt < 4; ++mt){
      bf16x8 a = *(const bf16x8*)&P1[mt * 16 + c][kk];
      acc[mt][0] = __builtin_amdgcn_mfma_f32_16x16x32_bf16(a, b0, acc[mt][0], 0, 0, 0);
      acc[mt][1] = __builtin_amdgcn_mfma_f32_16x16x32_bf16(a, b1, acc[mt][1], 0, 0, 0);
    }
  }

  float bf0 = b_ff[n0], bf1 = b_ff[n1];
  float sv0 = 0.f, sq0 = 0.f, sv1 = 0.f, sq1 = 0.f;
  float* outB = out + (size_t)b * EROW;
  #pragma unroll
  for (int mt = 0; mt < 4; ++mt){
    #pragma unroll
    for (int r = 0; r < 4; ++r){
      int m = mt * 16 + q * 4 + r;
      if (m < RC){
        float v0 = acc[mt][0][r] + bf0 + bf2f(P2[m][n0]);
        float v1 = acc[mt][1][r] + bf1 + bf2f(P2[m][n1]);
        size_t ro = (size_t)(rbase + m + 1) * DD;
        outB[ro + n0] = v0;
        outB[ro + n1] = v1;
        sv0 += v0; sq0 += v0 * v0;
        sv1 += v1; sq1 += v1 * v1;
      }
    }
  }
  sv0 += __shfl_xor(sv0, 16); sv0 += __shfl_xor(sv0, 32);
  sq0 += __shfl_xor(sq0, 16); sq0 += __shfl_xor(sq0, 32);
  sv1 += __shfl_xor(sv1, 16); sv1 += __shfl_xor(sv1, 32);
  sq1 += __shfl_xor(sq1, 16); sq1 += __shfl_xor(sq1, 32);
  if (q == 0){
    atomicAdd(&sums [b * DD + n0], sv0);
    atomicAdd(&sumsq[b * DD + n0], sq0);
    atomicAdd(&sums [b * DD + n1], sv1);
    atomicAdd(&sumsq[b * DD + n1], sq1);
  }
}

// ---------------- k1b: fold sums -> per-(b,d) scale/shift ----------------
__global__ __launch_bounds__(256) void k1b_stats(
    const float* __restrict__ sums, const float* __restrict__ sumsq,
    const float* __restrict__ nw, const float* __restrict__ nb,
    float* __restrict__ scale, float* __restrict__ shift)
{
  int t = blockIdx.x * 256 + threadIdx.x;   // exactly 8192
  int d = t & 127;
  float mean = sums[t] * (1.f / NN);
  float var  = sumsq[t] * (1.f / NN) - mean * mean;
  float inv  = rsqrtf(var + 1e-5f);
  float sc = inv * nw[d];
  scale[t] = sc;
  shift[t] = nb[d] - mean * sc;
}

// ---------------- k2: in-place layernorm apply over rows 1..N ----------------
__global__ __launch_bounds__(256) void k2_norm(
    float* __restrict__ out, const float* __restrict__ scale, const float* __restrict__ shift)
{
  size_t t = (size_t)blockIdx.x * 256 + threadIdx.x;   // 5,120,000 threads, 8 f32 each
  size_t e = t * 8;
  int b = (int)(e / CROW);
  int rem = (int)(e - (size_t)b * CROW);
  int d = rem & 127;
  const float4 s0 = *(const float4*)&scale[b * DD + d];
  const float4 s1 = *(const float4*)&scale[b * DD + d + 4];
  const float4 h0 = *(const float4*)&shift[b * DD + d];
  const float4 h1 = *(const float4*)&shift[b * DD + d + 4];
  float4* p = (float4*)(out + (size_t)b * EROW + DD + rem);
  float4 v0 = p[0], v1 = p[1];
  v0.x = v0.x * s0.x + h0.x; v0.y = v0.y * s0.y + h0.y;
  v0.z = v0.z * s0.z + h0.z; v0.w = v0.w * s0.w + h0.w;
  v1.x = v1.x * s1.x + h1.x; v1.y = v1.y * s1.y + h1.y;
  v1.z = v1.z * s1.z + h1.z; v1.w = v1.w * s1.w + h1.w;
  p[0] = v0; p[1] = v1;
}

extern "C" void kernel_launch(void* const* d_in, const int* in_sizes, int n_in,
                              void* d_out, int out_size, void* d_ws, size_t ws_size,
                              hipStream_t stream)
{
  const int2*  sol  = (const int2*) d_in[2];
  const float* emb  = (const float*)d_in[3];
  const float* wl   = (const float*)d_in[4];
  const float* wr   = (const float*)d_in[5];
  const float* wcmb = (const float*)d_in[6];
  const float* bcmb = (const float*)d_in[7];
  const float* wff  = (const float*)d_in[8];
  const float* bff  = (const float*)d_in[9];
  const float* nw   = (const float*)d_in[10];
  const float* nb   = (const float*)d_in[11];
  float* out = (float*)d_out;

  u16*   wbf   = (u16*)d_ws;                           // 81920 bf16 = 163840 B
  float* sums  = (float*)((char*)d_ws + 163840);       // 8192 f32
  float* sumsq = (float*)((char*)d_ws + 196608);       // 8192 f32
  float* scale = (float*)((char*)d_ws + 229376);       // 8192 f32
  float* shift = (float*)((char*)d_ws + 262144);       // 8192 f32

  k0_prep <<<320, 256, 0, stream>>>(wl, wr, wcmb, wff, emb, out, wbf, sums, sumsq);
  k1_main <<<dim3(79, 64), 256, 0, stream>>>(sol, emb, wbf, bcmb, bff, out, sums, sumsq);
  k1b_stats<<<32, 256, 0, stream>>>(sums, sumsq, nw, nb, scale, shift);
  k2_norm <<<20000, 256, 0, stream>>>(out, scale, shift);
}

// Round 2
// 483.892 us; speedup vs baseline: 1.0427x; 1.0427x over previous
//
#include <hip/hip_runtime.h>

typedef unsigned short u16;
typedef __attribute__((ext_vector_type(8))) short bf16x8;
typedef __attribute__((ext_vector_type(4))) float f32x4;

#define BB 64
#define NN 5000
#define DD 128
#define EROW 640128   // (NN+1)*DD
#define CROW 640000   // NN*DD

__device__ __forceinline__ u16 f2bf(float f){
  unsigned u = __builtin_bit_cast(unsigned, f);
  u += 0x7fffu + ((u >> 16) & 1u);   // round-to-nearest-even
  return (u16)(u >> 16);
}
__device__ __forceinline__ float bf2f(u16 h){
  unsigned u = ((unsigned)h) << 16;
  return __builtin_bit_cast(float, u);
}

// ---------------- k0: weight bf16 conversion, accumulator zeroing, depot copy ----------------
__global__ __launch_bounds__(256) void k0_prep(
    const float* __restrict__ wl, const float* __restrict__ wr,
    const float* __restrict__ wcmb, const float* __restrict__ wff,
    const float* __restrict__ emb, float* __restrict__ out,
    u16* __restrict__ wbf, float* __restrict__ sums, float* __restrict__ sumsq)
{
  int t = blockIdx.x * 256 + threadIdx.x;   // grid covers exactly 81920
  if      (t < 16384) wbf[t] = f2bf(wl[t]);
  else if (t < 32768) wbf[t] = f2bf(wr[t - 16384]);
  else if (t < 65536) wbf[t] = f2bf(wcmb[t - 32768]);
  else                wbf[t] = f2bf(wff[t - 65536]);
  if (t < 8192){
    sums[t] = 0.f; sumsq[t] = 0.f;
    int b = t >> 7, d = t & 127;
    out[(size_t)b * EROW + d] = emb[(size_t)b * EROW + d];   // depot row passthrough
  }
}

// ---------------- k1: fused gather + 3 GEMMs + residual ----------------
// 2 LDS buffers (35 KB) -> 4 blocks/CU.  A: left -> info -> h -> added(bf16)
//                                        B: right -> cust (live to end, residual)
// BF=true: write added bf16 to abuf (k2 reads it).  BF=false: write fp32 to out (RMW k2).
template<bool BF>
__global__ __launch_bounds__(256, 4)
void k1_main(const int2* __restrict__ sol, const float* __restrict__ emb,
             const u16* __restrict__ wbf, const float* __restrict__ b_comb,
             const float* __restrict__ b_ff, float* __restrict__ out,
             u16* __restrict__ abuf, float* __restrict__ sums, float* __restrict__ sumsq)
{
  const int tid  = threadIdx.x;
  const int lane = tid & 63;
  const int wave = tid >> 6;
  const int q    = lane >> 4;
  const int c    = lane & 15;
  const int tile = blockIdx.x;
  const int b    = blockIdx.y;
  const int rbase = tile * 64;
  const int RC = min(64, NN - rbase);

  // pad 136 (=128+8): rows stay 16B-aligned (272B stride)
  __shared__ u16 A[64][136];
  __shared__ u16 Bb[64][136];
  __shared__ int sIL[64], sIR[64];

  if (tid < 64){
    int r = rbase + tid; r = min(r, NN - 1);
    int2 p = sol[(size_t)b * NN + r];
    sIL[tid] = p.x; sIR[tid] = p.y;
  }
  __syncthreads();

  const float* embB = emb + (size_t)b * EROW;
  const int gi = tid >> 2, gsub = tid & 3;

  { // gather left->A, right->B
    int il = sIL[gi], ir = sIR[gi];
    const float4* vL = (const float4*)(embB + (size_t)il * DD) + gsub * 8;
    const float4* vR = (const float4*)(embB + (size_t)ir * DD) + gsub * 8;
    #pragma unroll
    for (int j = 0; j < 8; ++j){
      float4 a = vL[j], bb = vR[j];
      int col = gsub * 32 + j * 4;
      ushort4 ua = {f2bf(a.x),  f2bf(a.y),  f2bf(a.z),  f2bf(a.w)};
      ushort4 ub = {f2bf(bb.x), f2bf(bb.y), f2bf(bb.z), f2bf(bb.w)};
      *(ushort4*)&A[gi][col]  = ua;
      *(ushort4*)&Bb[gi][col] = ub;
    }
  }
  __syncthreads();

  const int n0 = wave * 32 + c;   // this wave owns output cols [wave*32, wave*32+32)
  const int n1 = n0 + 16;

  const u16* wl = wbf;            // [128][128] bf16
  const u16* wr = wbf + 16384;    // [128][128]
  const u16* wc = wbf + 32768;    // [128][256]
  const u16* wf = wbf + 65536;    // [128][128]

  const f32x4 fz = {0.f, 0.f, 0.f, 0.f};
  f32x4 acc[4][2];

  // ---- GEMM1: info = left @ Wl^T + right @ Wr^T (K = 128+128) ----
  #pragma unroll
  for (int mt = 0; mt < 4; ++mt){ acc[mt][0] = fz; acc[mt][1] = fz; }
  #pragma unroll
  for (int ks = 0; ks < 8; ++ks){
    const u16* W = (ks < 4) ? wl : wr;
    const int kk = (ks & 3) * 32 + q * 8;
    bf16x8 b0 = *(const bf16x8*)(W + n0 * 128 + kk);
    bf16x8 b1 = *(const bf16x8*)(W + n1 * 128 + kk);
    #pragma unroll
    for (int mt = 0; mt < 4; ++mt){
      bf16x8 a = *(const bf16x8*)&((ks < 4) ? A : Bb)[mt * 16 + c][kk];
      acc[mt][0] = __builtin_amdgcn_mfma_f32_16x16x32_bf16(a, b0, acc[mt][0], 0, 0, 0);
      acc[mt][1] = __builtin_amdgcn_mfma_f32_16x16x32_bf16(a, b1, acc[mt][1], 0, 0, 0);
    }
  }
  __syncthreads();   // all reads of A/B done

  // info -> A ; gather cust -> B
  #pragma unroll
  for (int mt = 0; mt < 4; ++mt){
    #pragma unroll
    for (int r = 0; r < 4; ++r){
      int m = mt * 16 + q * 4 + r;   // C/D layout: row=(lane>>4)*4+reg, col=lane&15
      A[m][n0] = f2bf(acc[mt][0][r]);
      A[m][n1] = f2bf(acc[mt][1][r]);
    }
  }
  { // cust gather: contiguous rows rbase+1 .. rbase+64 (clamped)
    int crow = min(rbase + gi + 1, NN);
    const float4* vC = (const float4*)(embB + (size_t)crow * DD) + gsub * 8;
    #pragma unroll
    for (int j = 0; j < 8; ++j){
      float4 cc = vC[j];
      int col = gsub * 32 + j * 4;
      ushort4 uc = {f2bf(cc.x), f2bf(cc.y), f2bf(cc.z), f2bf(cc.w)};
      *(ushort4*)&Bb[gi][col] = uc;
    }
  }
  __syncthreads();

  // ---- GEMM2: h = relu([cust | info] @ Wcomb^T + b_comb) (K = 256) ----
  #pragma unroll
  for (int mt = 0; mt < 4; ++mt){ acc[mt][0] = fz; acc[mt][1] = fz; }
  #pragma unroll
  for (int ks = 0; ks < 8; ++ks){
    const int kk = (ks & 3) * 32 + q * 8;
    const int kg = ks * 32 + q * 8;
    bf16x8 b0 = *(const bf16x8*)(wc + n0 * 256 + kg);
    bf16x8 b1 = *(const bf16x8*)(wc + n1 * 256 + kg);
    #pragma unroll
    for (int mt = 0; mt < 4; ++mt){
      bf16x8 a = *(const bf16x8*)&((ks < 4) ? Bb : A)[mt * 16 + c][kk];
      acc[mt][0] = __builtin_amdgcn_mfma_f32_16x16x32_bf16(a, b0, acc[mt][0], 0, 0, 0);
      acc[mt][1] = __builtin_amdgcn_mfma_f32_16x16x32_bf16(a, b1, acc[mt][1], 0, 0, 0);
    }
  }
  __syncthreads();   // all reads of A(info)/B(cust) for GEMM2 done
  {
    float bc0 = b_comb[n0], bc1 = b_comb[n1];
    #pragma unroll
    for (int mt = 0; mt < 4; ++mt){
      #pragma unroll
      for (int r = 0; r < 4; ++r){
        int m = mt * 16 + q * 4 + r;
        A[m][n0] = f2bf(fmaxf(acc[mt][0][r] + bc0, 0.f));   // h -> A (info dead)
        A[m][n1] = f2bf(fmaxf(acc[mt][1][r] + bc1, 0.f));
      }
    }
  }
  __syncthreads();

  // ---- GEMM3: h2 = h @ Wff^T + b_ff;  added = cust + h2 ----
  #pragma unroll
  for (int mt = 0; mt < 4; ++mt){ acc[mt][0] = fz; acc[mt][1] = fz; }
  #pragma unroll
  for (int ks = 0; ks < 4; ++ks){
    const int kk = ks * 32 + q * 8;
    bf16x8 b0 = *(const bf16x8*)(wf + n0 * 128 + kk);
    bf16x8 b1 = *(const bf16x8*)(wf + n1 * 128 + kk);
    #pragma unroll
    for (int mt = 0; mt < 4; ++mt){
      bf16x8 a = *(const bf16x8*)&A[mt * 16 + c][kk];
      acc[mt][0] = __builtin_amdgcn_mfma_f32_16x16x32_bf16(a, b0, acc[mt][0], 0, 0, 0);
      acc[mt][1] = __builtin_amdgcn_mfma_f32_16x16x32_bf16(a, b1, acc[mt][1], 0, 0, 0);
    }
  }

  const float bf0 = b_ff[n0], bf1 = b_ff[n1];
  float sv0 = 0.f, sq0 = 0.f, sv1 = 0.f, sq1 = 0.f;
  float* outB = out + (size_t)b * EROW;
  #pragma unroll
  for (int mt = 0; mt < 4; ++mt){
    #pragma unroll
    for (int r = 0; r < 4; ++r){
      int m = mt * 16 + q * 4 + r;
      float v0 = acc[mt][0][r] + bf0 + bf2f(Bb[m][n0]);   // residual from cust
      float v1 = acc[mt][1][r] + bf1 + bf2f(Bb[m][n1]);
      acc[mt][0][r] = v0; acc[mt][1][r] = v1;
      if (m < RC){
        sv0 += v0; sq0 += v0 * v0;
        sv1 += v1; sq1 += v1 * v1;
        if (!BF){
          size_t ro = (size_t)(rbase + m + 1) * DD;
          outB[ro + n0] = v0;
          outB[ro + n1] = v1;
        }
      }
    }
  }
  sv0 += __shfl_xor(sv0, 16); sv0 += __shfl_xor(sv0, 32);
  sq0 += __shfl_xor(sq0, 16); sq0 += __shfl_xor(sq0, 32);
  sv1 += __shfl_xor(sv1, 16); sv1 += __shfl_xor(sv1, 32);
  sq1 += __shfl_xor(sq1, 16); sq1 += __shfl_xor(sq1, 32);
  if (q == 0){
    atomicAdd(&sums [b * DD + n0], sv0);
    atomicAdd(&sumsq[b * DD + n0], sq0);
    atomicAdd(&sums [b * DD + n1], sv1);
    atomicAdd(&sumsq[b * DD + n1], sq1);
  }

  if (BF){
    __syncthreads();   // GEMM3 A-reads + residual B-reads complete
    // added (bf16) -> A, then coalesced 16B copy-out
    #pragma unroll
    for (int mt = 0; mt < 4; ++mt){
      #pragma unroll
      for (int r = 0; r < 4; ++r){
        int m = mt * 16 + q * 4 + r;
        A[m][n0] = f2bf(acc[mt][0][r]);
        A[m][n1] = f2bf(acc[mt][1][r]);
      }
    }
    __syncthreads();
    const int row = tid >> 2, cb = tid & 3;
    if (rbase + row < NN){
      u16* dst = abuf + ((size_t)b * NN + rbase + row) * DD + cb * 32;
      #pragma unroll
      for (int j = 0; j < 4; ++j)
        *(bf16x8*)(dst + j * 8) = *(const bf16x8*)&A[row][cb * 32 + j * 8];
    }
  }
}

// ---------------- k1b: fold sums -> per-(b,d) scale/shift ----------------
__global__ __launch_bounds__(256) void k1b_stats(
    const float* __restrict__ sums, const float* __restrict__ sumsq,
    const float* __restrict__ nw, const float* __restrict__ nb,
    float* __restrict__ scale, float* __restrict__ shift)
{
  int t = blockIdx.x * 256 + threadIdx.x;   // exactly 8192
  int d = t & 127;
  float mean = sums[t] * (1.f / NN);
  float var  = sumsq[t] * (1.f / NN) - mean * mean;
  float inv  = rsqrtf(var + 1e-5f);
  float sc = inv * nw[d];
  scale[t] = sc;
  shift[t] = nb[d] - mean * sc;
}

// ---------------- k2 (bf path): read bf16 added, write normalized fp32 out ----------------
__global__ __launch_bounds__(256) void k2_bf(
    const u16* __restrict__ abuf, const float* __restrict__ scale,
    const float* __restrict__ shift, float* __restrict__ out)
{
  const int b = blockIdx.y;
  const int e = (blockIdx.x * 256 + threadIdx.x) * 8;   // within-batch flat index
  if (e >= CROW) return;
  const int d = e & 127;
  const uint4 raw = *(const uint4*)(abuf + (size_t)b * CROW + e);
  const float4 s0 = *(const float4*)&scale[b * DD + d];
  const float4 s1 = *(const float4*)&scale[b * DD + d + 4];
  const float4 h0 = *(const float4*)&shift[b * DD + d];
  const float4 h1 = *(const float4*)&shift[b * DD + d + 4];
  float4 v0, v1;
  v0.x = __builtin_bit_cast(float, raw.x << 16);
  v0.y = __builtin_bit_cast(float, raw.x & 0xffff0000u);
  v0.z = __builtin_bit_cast(float, raw.y << 16);
  v0.w = __builtin_bit_cast(float, raw.y & 0xffff0000u);
  v1.x = __builtin_bit_cast(float, raw.z << 16);
  v1.y = __builtin_bit_cast(float, raw.z & 0xffff0000u);
  v1.z = __builtin_bit_cast(float, raw.w << 16);
  v1.w = __builtin_bit_cast(float, raw.w & 0xffff0000u);
  v0.x = v0.x * s0.x + h0.x; v0.y = v0.y * s0.y + h0.y;
  v0.z = v0.z * s0.z + h0.z; v0.w = v0.w * s0.w + h0.w;
  v1.x = v1.x * s1.x + h1.x; v1.y = v1.y * s1.y + h1.y;
  v1.z = v1.z * s1.z + h1.z; v1.w = v1.w * s1.w + h1.w;
  float4* p = (float4*)(out + (size_t)b * EROW + DD + e);
  p[0] = v0; p[1] = v1;
}

// ---------------- k2 (fallback): in-place RMW layernorm ----------------
__global__ __launch_bounds__(256) void k2_rmw(
    float* __restrict__ out, const float* __restrict__ scale, const float* __restrict__ shift)
{
  const int b = blockIdx.y;
  const int e = (blockIdx.x * 256 + threadIdx.x) * 8;
  if (e >= CROW) return;
  const int d = e & 127;
  const float4 s0 = *(const float4*)&scale[b * DD + d];
  const float4 s1 = *(const float4*)&scale[b * DD + d + 4];
  const float4 h0 = *(const float4*)&shift[b * DD + d];
  const float4 h1 = *(const float4*)&shift[b * DD + d + 4];
  float4* p = (float4*)(out + (size_t)b * EROW + DD + e);
  float4 v0 = p[0], v1 = p[1];
  v0.x = v0.x * s0.x + h0.x; v0.y = v0.y * s0.y + h0.y;
  v0.z = v0.z * s0.z + h0.z; v0.w = v0.w * s0.w + h0.w;
  v1.x = v1.x * s1.x + h1.x; v1.y = v1.y * s1.y + h1.y;
  v1.z = v1.z * s1.z + h1.z; v1.w = v1.w * s1.w + h1.w;
  p[0] = v0; p[1] = v1;
}

extern "C" void kernel_launch(void* const* d_in, const int* in_sizes, int n_in,
                              void* d_out, int out_size, void* d_ws, size_t ws_size,
                              hipStream_t stream)
{
  const int2*  sol  = (const int2*) d_in[2];
  const float* emb  = (const float*)d_in[3];
  const float* wl   = (const float*)d_in[4];
  const float* wr   = (const float*)d_in[5];
  const float* wcmb = (const float*)d_in[6];
  const float* bcmb = (const float*)d_in[7];
  const float* wff  = (const float*)d_in[8];
  const float* bff  = (const float*)d_in[9];
  const float* nw   = (const float*)d_in[10];
  const float* nb   = (const float*)d_in[11];
  float* out = (float*)d_out;

  u16*   wbf   = (u16*)d_ws;                           // 81920 bf16 = 163840 B
  float* sums  = (float*)((char*)d_ws + 163840);       // 8192 f32
  float* sumsq = (float*)((char*)d_ws + 196608);       // 8192 f32
  float* scale = (float*)((char*)d_ws + 229376);       // 8192 f32
  float* shift = (float*)((char*)d_ws + 262144);       // 8192 f32
  u16*   abuf  = (u16*)((char*)d_ws + 294912);         // 64*5000*128 bf16 = 81.92 MB

  const size_t need = 294912ull + (size_t)BB * NN * DD * 2;
  const bool bfpath = (ws_size >= need);

  k0_prep <<<320, 256, 0, stream>>>(wl, wr, wcmb, wff, emb, out, wbf, sums, sumsq);
  if (bfpath){
    k1_main<true> <<<dim3(79, 64), 256, 0, stream>>>(sol, emb, wbf, bcmb, bff, out, abuf, sums, sumsq);
    k1b_stats<<<32, 256, 0, stream>>>(sums, sumsq, nw, nb, scale, shift);
    k2_bf  <<<dim3(313, 64), 256, 0, stream>>>(abuf, scale, shift, out);
  } else {
    k1_main<false><<<dim3(79, 64), 256, 0, stream>>>(sol, emb, wbf, bcmb, bff, out, abuf, sums, sumsq);
    k1b_stats<<<32, 256, 0, stream>>>(sums, sumsq, nw, nb, scale, shift);
    k2_rmw <<<dim3(313, 64), 256, 0, stream>>>(out, scale, shift);
  }
}